// Round 1
// baseline (1946.094 us; speedup 1.0000x reference)
//
#include <hip/hip_runtime.h>
#include <stdint.h>
#include <math.h>

// OptimalTransportLoss: b=64 pairs^2, n=128, d=128.
// ws layout (floats): [0]=cost_min, [1]=cost_span, [2 .. 8193]=per-block sq min/max pairs,
//                     [8194 .. 12289]=raw distances per (i,j) block.

typedef _Float16 h2 __attribute__((ext_vector_type(2)));

__device__ __forceinline__ h2 bch2(uint32_t u) { return __builtin_bit_cast(h2, u); }
__device__ __forceinline__ uint32_t pkh2(float x, float y) {
  h2 h = {(_Float16)x, (_Float16)y};
  return __builtin_bit_cast(uint32_t, h);
}
__device__ __forceinline__ float rnd16(float x) { return (float)(_Float16)x; }

__device__ __forceinline__ float fdot2f(h2 a, h2 b, float c) {
#if __has_builtin(__builtin_amdgcn_fdot2)
  return __builtin_amdgcn_fdot2(a, b, c, false);
#else
  return fmaf((float)a[0], (float)b[0], fmaf((float)a[1], (float)b[1], c));
#endif
}

// Stage one 128x128 f32 block of eeg[i] and text[j] into LDS as fp16 pairs,
// XOR-swizzled within each 64-dword row: phys = p ^ ((row&7)<<2).
__device__ __forceinline__ void stage_et(const float* __restrict__ ep,
                                         const float* __restrict__ tp,
                                         uint32_t* eL, uint32_t* tL, int t) {
  const float4* e4 = (const float4*)ep;
  const float4* t4 = (const float4*)tp;
#pragma unroll
  for (int k = 0; k < 16; ++k) {
    int F = k * 256 + t;          // float4 index, 4096 total
    int n = F >> 5, g = F & 31;   // row, float4-group in row
    int idx = n * 64 + ((2 * g) ^ ((n & 7) << 2));  // even; +1 stays in pair
    float4 x = e4[F];
    eL[idx]     = pkh2(x.x, x.y);
    eL[idx + 1] = pkh2(x.z, x.w);
    float4 y = t4[F];
    tL[idx]     = pkh2(y.x, y.y);
    tL[idx + 1] = pkh2(y.z, y.w);
  }
}

// e2/t2: squared norms per row, fp16-rounded (reference computes them in fp16).
__device__ __forceinline__ void sqnorms(const uint32_t* eL, const uint32_t* tL,
                                        float* e2a, float* t2a, int t) {
  int n = t & 127;
  const uint32_t* src = (t < 128) ? eL : tL;   // wave-uniform (waves 0,1 vs 2,3)
  int sw = (n & 7) << 2;
  float a0 = 0.f, a1 = 0.f;
#pragma unroll
  for (int p = 0; p < 64; p += 2) {
    h2 x = bch2(src[n * 64 + (p ^ sw)]);
    h2 y = bch2(src[n * 64 + ((p + 1) ^ sw)]);
    a0 = fdot2f(x, x, a0);
    a1 = fdot2f(y, y, a1);
  }
  float r = rnd16(a0 + a1);
  if (t < 128) e2a[n] = r; else t2a[n] = r;
}

// ---------------- Phase A: per-block min/max of sq (pre-sqrt, monotone) -------------
__global__ __launch_bounds__(256, 2) void phaseA(const float* __restrict__ eeg,
                                                 const float* __restrict__ text,
                                                 float* __restrict__ ws) {
  extern __shared__ char smem[];
  uint32_t* eL = (uint32_t*)smem;              // 32768 B
  uint32_t* tL = (uint32_t*)(smem + 32768);    // 32768 B
  float* e2a   = (float*)(smem + 65536);       // 512 B
  float* t2a   = (float*)(smem + 66048);       // 512 B
  float* red   = (float*)(smem + 66560);       // 32 B
  int t = threadIdx.x;
  int b = blockIdx.x;
  const float* ep = eeg + (size_t)(b >> 6) * 16384;
  const float* tp = text + (size_t)(b & 63) * 16384;

  stage_et(ep, tp, eL, tL, t);
  __syncthreads();
  sqnorms(eL, tL, e2a, t2a, t);
  __syncthreads();

  int n = t >> 1, h = t & 1;
  int swn = (n & 7) << 2;
  uint32_t er[64];
#pragma unroll
  for (int p = 0; p < 64; ++p) er[p] = eL[n * 64 + (p ^ swn)];
  float e2r = e2a[n];
  float smn = 1e30f, smx = -1e30f;
  for (int j = 0; j < 64; ++j) {
    int m = h * 64 + j;
    const uint32_t* trow = tL + m * 64;
    int swm = (m & 7) << 2;
    float a0 = 0.f, a1 = 0.f, a2 = 0.f, a3 = 0.f;
#pragma unroll
    for (int p = 0; p < 64; p += 4) {
      a0 = fdot2f(bch2(er[p]),     bch2(trow[(p)     ^ swm]), a0);
      a1 = fdot2f(bch2(er[p + 1]), bch2(trow[(p + 1) ^ swm]), a1);
      a2 = fdot2f(bch2(er[p + 2]), bch2(trow[(p + 2) ^ swm]), a2);
      a3 = fdot2f(bch2(er[p + 3]), bch2(trow[(p + 3) ^ swm]), a3);
    }
    float ip = rnd16((a0 + a1) + (a2 + a3));
    float sq = fmaxf(fmaf(-2.0f, ip, e2r + t2a[m]), 0.0f);
    smn = fminf(smn, sq);
    smx = fmaxf(smx, sq);
  }
#pragma unroll
  for (int msk = 1; msk < 64; msk <<= 1) {
    smn = fminf(smn, __shfl_xor(smn, msk));
    smx = fmaxf(smx, __shfl_xor(smx, msk));
  }
  if ((t & 63) == 0) { red[t >> 6] = smn; red[4 + (t >> 6)] = smx; }
  __syncthreads();
  if (t == 0) {
    float mn = fminf(fminf(red[0], red[1]), fminf(red[2], red[3]));
    float mx = fmaxf(fmaxf(red[4], red[5]), fmaxf(red[6], red[7]));
    ws[2 + 2 * b] = mn;
    ws[3 + 2 * b] = mx;
  }
}

// ---------------- Phase B: reduce 4096 block min/max -> cost_min, cost_span ---------
__global__ void phaseB(float* __restrict__ ws) {
  __shared__ float red[16];
  int t = threadIdx.x;
  float mn = 1e30f, mx = -1e30f;
#pragma unroll
  for (int k = 0; k < 16; ++k) {
    int idx = k * 256 + t;
    mn = fminf(mn, ws[2 + 2 * idx]);
    mx = fmaxf(mx, ws[3 + 2 * idx]);
  }
#pragma unroll
  for (int msk = 1; msk < 64; msk <<= 1) {
    mn = fminf(mn, __shfl_xor(mn, msk));
    mx = fmaxf(mx, __shfl_xor(mx, msk));
  }
  if ((t & 63) == 0) { red[t >> 6] = mn; red[8 + (t >> 6)] = mx; }
  __syncthreads();
  if (t == 0) {
    mn = fminf(fminf(red[0], red[1]), fminf(red[2], red[3]));
    mx = fmaxf(fmaxf(red[8], red[9]), fmaxf(red[10], red[11]));
    float cmn = rnd16(sqrtf(rnd16(mn)));   // fp16-rounded cost, like reference
    float cmx = rnd16(sqrtf(rnd16(mx)));
    ws[0] = cmn;
    ws[1] = cmx - cmn;
  }
}

// ---------------- Phase C: build K in LDS, Sinkhorn via u/v matvecs, distance -------
#define OT_REG 0.1f
__global__ __launch_bounds__(256, 1) void phaseC(const float* __restrict__ eeg,
                                                 const float* __restrict__ text,
                                                 float* __restrict__ ws) {
  extern __shared__ char smem[];
  float* Kf = (float*)smem;                    // 65536 B (overlaps staging)
  float* KT = (float*)(smem + 65536);          // 65536 B
  uint32_t* eL = (uint32_t*)smem;              // staging overlay
  uint32_t* tL = (uint32_t*)(smem + 32768);
  float* uu  = (float*)(smem + 131072);        // 512 B
  float* vv  = (float*)(smem + 131584);        // 512 B
  float* red = (float*)(smem + 132096);        // 32 B
  float* e2a = (float*)(smem + 132128);        // 512 B (tail: safe vs KT writes)
  float* t2a = (float*)(smem + 132640);        // 512 B  -> total 133152 B
  int t = threadIdx.x;
  int b = blockIdx.x;
  const float* ep = eeg + (size_t)(b >> 6) * 16384;
  const float* tp = text + (size_t)(b & 63) * 16384;

  stage_et(ep, tp, eL, tL, t);
  __syncthreads();
  sqnorms(eL, tL, e2a, t2a, t);
  __syncthreads();

  float cmn = ws[0];
  float kexp2 = 1.4426950408889634f / (OT_REG * ws[1]);  // log2e / (reg*span)

  int n = t >> 1, h = t & 1;
  int swn = (n & 7) << 2;
  {
    uint32_t er[64];
#pragma unroll
    for (int p = 0; p < 64; ++p) er[p] = eL[n * 64 + (p ^ swn)];
    float e2r = e2a[n];
    for (int j = 0; j < 64; ++j) {
      int m = h * 64 + j;
      const uint32_t* trow = tL + m * 64;
      int swm = (m & 7) << 2;
      float a0 = 0.f, a1 = 0.f, a2 = 0.f, a3 = 0.f;
#pragma unroll
      for (int p = 0; p < 64; p += 4) {
        a0 = fdot2f(bch2(er[p]),     bch2(trow[(p)     ^ swm]), a0);
        a1 = fdot2f(bch2(er[p + 1]), bch2(trow[(p + 1) ^ swm]), a1);
        a2 = fdot2f(bch2(er[p + 2]), bch2(trow[(p + 2) ^ swm]), a2);
        a3 = fdot2f(bch2(er[p + 3]), bch2(trow[(p + 3) ^ swm]), a3);
      }
      float ip = rnd16((a0 + a1) + (a2 + a3));              // identical to phaseA
      float sq = fmaxf(fmaf(-2.0f, ip, e2r + t2a[m]), 0.0f);
      float c  = rnd16(sqrtf(rnd16(sq)));
      float kv = exp2f((cmn - c) * kexp2);                  // K = exp(-(c-mn)/(span*reg))
      KT[m * 128 + (n ^ swm)] = kv;   // safe: staging region untouched until barrier
    }
  }
  __syncthreads();

  // Fill K (row-major) from KT; accumulate S = sum(K).
  float ksum = 0.f;
#pragma unroll
  for (int j = 0; j < 64; ++j) {
    int m = h * 64 + j;
    float kv = KT[m * 128 + (n ^ ((m & 7) << 2))];
    Kf[n * 128 + (m ^ swn)] = kv;
    ksum += kv;
  }
#pragma unroll
  for (int msk = 1; msk < 64; msk <<= 1) ksum += __shfl_xor(ksum, msk);
  if ((t & 63) == 0) red[t >> 6] = ksum;
  __syncthreads();
  float S = (red[0] + red[1]) + (red[2] + red[3]);
  if (t < 128) { uu[t] = 1.0f / S; vv[t] = 1.0f; }   // T0 = K / sum(K)
  __syncthreads();

  const float4* K4  = (const float4*)Kf;
  const float4* KT4 = (const float4*)KT;
  const float4* U4  = (const float4*)uu;
  const float4* V4  = (const float4*)vv;
  int sw3 = n & 7;

  for (int it = 0; it < 100; ++it) {
    // row sweep: w = K v ; u <- u / (u*w + STAB)
    float ax = 0.f, ay = 0.f, az = 0.f, aw = 0.f;
#pragma unroll
    for (int q = 0; q < 16; ++q) {
      int G = h * 16 + q;
      float4 kk = K4[n * 32 + (G ^ sw3)];
      float4 vq = V4[G];
      ax = fmaf(kk.x, vq.x, ax); ay = fmaf(kk.y, vq.y, ay);
      az = fmaf(kk.z, vq.z, az); aw = fmaf(kk.w, vq.w, aw);
    }
    float w = (ax + ay) + (az + aw);
    w += __shfl_xor(w, 1);
    float uo = uu[n];
    float un = uo / (uo * w + 1e-8f);
    if (h == 0) uu[n] = un;
    __syncthreads();

    // col sweep: z = K^T u ; v <- v / (v*z + STAB); convergence dev = |colsum-1|
    ax = ay = az = aw = 0.f;
#pragma unroll
    for (int q = 0; q < 16; ++q) {
      int G = h * 16 + q;
      float4 kk = KT4[n * 32 + (G ^ sw3)];
      float4 uq = U4[G];
      ax = fmaf(kk.x, uq.x, ax); ay = fmaf(kk.y, uq.y, ay);
      az = fmaf(kk.z, uq.z, az); aw = fmaf(kk.w, uq.w, aw);
    }
    float z = (ax + ay) + (az + aw);
    z += __shfl_xor(z, 1);
    float vo = vv[n];
    float cs = vo * z;
    float vn = vo / (cs + 1e-8f);
    if (h == 0) vv[n] = vn;
    float dev = fabsf(cs - 1.0f);
#pragma unroll
    for (int msk = 1; msk < 64; msk <<= 1) dev = fmaxf(dev, __shfl_xor(dev, msk));
    if ((t & 63) == 0) red[t >> 6] = dev;
    __syncthreads();
    float bd = fmaxf(fmaxf(red[0], red[1]), fmaxf(red[2], red[3]));
    if (bd < 4e-6f) break;   // uniform; further ref iterations change T by <1e-4 rel
  }

  // distance = sum u K v * cost_n, cost_n = -reg * ln(K)
  __syncthreads();
  float acc = 0.f;
#pragma unroll
  for (int q = 0; q < 16; ++q) {
    int G = h * 16 + q;
    float4 kk = K4[n * 32 + (G ^ sw3)];
    float4 vq = V4[G];
    acc += kk.x * vq.x * __log2f(kk.x);
    acc += kk.y * vq.y * __log2f(kk.y);
    acc += kk.z * vq.z * __log2f(kk.z);
    acc += kk.w * vq.w * __log2f(kk.w);
  }
  acc *= uu[n] * (-OT_REG * 0.69314718055994531f);
#pragma unroll
  for (int msk = 1; msk < 64; msk <<= 1) acc += __shfl_xor(acc, msk);
  if ((t & 63) == 0) red[t >> 6] = acc;
  __syncthreads();
  if (t == 0) ws[8194 + b] = (red[0] + red[1]) + (red[2] + red[3]);
}

// ---------------- Phase D: minmax(d) -> similarity -> CE loss ------------------------
__global__ void phaseD(const float* __restrict__ ws, float* __restrict__ out) {
  __shared__ float sim[4096];
  __shared__ float red[16];
  int t = threadIdx.x;
  const float* d = ws + 8194;
  float dv[16];
  float mn = 1e30f, mx = -1e30f;
#pragma unroll
  for (int k = 0; k < 16; ++k) {
    dv[k] = d[k * 256 + t];
    mn = fminf(mn, dv[k]);
    mx = fmaxf(mx, dv[k]);
  }
#pragma unroll
  for (int msk = 1; msk < 64; msk <<= 1) {
    mn = fminf(mn, __shfl_xor(mn, msk));
    mx = fmaxf(mx, __shfl_xor(mx, msk));
  }
  if ((t & 63) == 0) { red[t >> 6] = mn; red[8 + (t >> 6)] = mx; }
  __syncthreads();
  mn = fminf(fminf(red[0], red[1]), fminf(red[2], red[3]));
  mx = fmaxf(fmaxf(red[8], red[9]), fmaxf(red[10], red[11]));
  float inv = 1.0f / (mx - mn);
#pragma unroll
  for (int k = 0; k < 16; ++k) {
    int idx = k * 256 + t;
    float s = expf(-(dv[k] - mn) * inv);
    sim[idx] = s;
    out[1 + idx] = s;
  }
  __syncthreads();
  if (t < 64) {
    float a = 0.f;
    for (int j = 0; j < 64; ++j) a += expf(sim[t * 64 + j]);
    float val = logf(a) - sim[t * 64 + t];   // lse_i - sim_ii
#pragma unroll
    for (int msk = 1; msk < 64; msk <<= 1) val += __shfl_xor(val, msk);
    if (t == 0) out[0] = val * (1.0f / 64.0f);  // loss = mean(lse - diag)
  }
}

extern "C" void kernel_launch(void* const* d_in, const int* in_sizes, int n_in,
                              void* d_out, int out_size, void* d_ws, size_t ws_size,
                              hipStream_t stream) {
  const float* eeg  = (const float*)d_in[0];
  const float* text = (const float*)d_in[1];
  float* out = (float*)d_out;
  float* ws  = (float*)d_ws;   // needs 12290 floats = 49160 B

  phaseA<<<4096, 256, 66592, stream>>>(eeg, text, ws);
  phaseB<<<1, 256, 0, stream>>>(ws);
  phaseC<<<4096, 256, 133152, stream>>>(eeg, text, ws);
  phaseD<<<1, 256, 0, stream>>>(ws, out);
}

// Round 2
// 930.391 us; speedup vs baseline: 2.0917x; 2.0917x over previous
//
#include <hip/hip_runtime.h>
#include <stdint.h>
#include <math.h>

// OptimalTransportLoss: b=64 pairs^2, n=128, d=128.
// ws floats: [0]=cost_min, [1]=cost_span, [2..8193]=per-block sq min/max pairs,
//            [8194..12289]=distances per (i,j) block.

typedef _Float16 h2 __attribute__((ext_vector_type(2)));

__device__ __forceinline__ h2 bch2(uint32_t u) { return __builtin_bit_cast(h2, u); }
__device__ __forceinline__ uint32_t pkh2(float x, float y) {
  h2 h = {(_Float16)x, (_Float16)y};
  return __builtin_bit_cast(uint32_t, h);
}
__device__ __forceinline__ float rnd16(float x) { return (float)(_Float16)x; }
__device__ __forceinline__ float fdot2f(h2 a, h2 b, float c) {
  return __builtin_amdgcn_fdot2(a, b, c, false);
}

// Stage 128x128 f32 blocks of eeg[i], text[j] into LDS as packed fp16 pairs.
// Swizzle: u32 p in row m stored at p ^ (((m>>3)&7)<<2)  (8-row granularity so the
// 8x8 build's same-thread rows share one swizzle, distinct thread-groups spread banks).
__device__ __forceinline__ void stage2(const float* __restrict__ ep,
                                       const float* __restrict__ tp,
                                       uint32_t* eL, uint32_t* tL, int t) {
  const float4* e4 = (const float4*)ep;
  const float4* t4 = (const float4*)tp;
#pragma unroll
  for (int k = 0; k < 16; ++k) {
    int F = k * 256 + t;          // float4 index, 4096 total
    int m = F >> 5, g = F & 31;   // row, float4-group in row
    int idx = m * 64 + ((2 * g) ^ (((m >> 3) & 7) << 2));  // even; +1 stays adjacent
    float4 x = e4[F];
    eL[idx]     = pkh2(x.x, x.y);
    eL[idx + 1] = pkh2(x.z, x.w);
    float4 y = t4[F];
    tL[idx]     = pkh2(y.x, y.y);
    tL[idx + 1] = pkh2(y.z, y.w);
  }
}

// fp16-rounded squared row norm (identical accumulation in phaseA and phaseC).
__device__ __forceinline__ float norm2of(const uint32_t* base, int sw) {
  float a0 = 0.f, a1 = 0.f;
#pragma unroll
  for (int kp = 0; kp < 32; ++kp) {
    uint2 u = *(const uint2*)(base + ((2 * kp) ^ sw));
    h2 x = bch2(u.x), y = bch2(u.y);
    a0 = fdot2f(x, x, a0);
    a1 = fdot2f(y, y, a1);
  }
  return rnd16(a0 + a1);
}

// 8x8 register-tiled inner products: thread (rg,cg) accumulates
// acc[r][c] = <e_row(8rg+r), t_row(8cg+c)> over d=128 (fp16 inputs, fp32 acc).
__device__ __forceinline__ void build8x8(const uint32_t* eL, const uint32_t* tL,
                                         int rg, int cg, float (&acc)[8][8]) {
  const uint32_t* eb = eL + rg * 8 * 64;
  const uint32_t* tb = tL + cg * 8 * 64;
  int swe = (rg & 7) << 2, swt = (cg & 7) << 2;
#pragma unroll 4
  for (int kp = 0; kp < 32; ++kp) {
    int phe = (2 * kp) ^ swe, pht = (2 * kp) ^ swt;
    uint2 av[8], bv[8];
#pragma unroll
    for (int r = 0; r < 8; ++r) av[r] = *(const uint2*)(eb + r * 64 + phe);
#pragma unroll
    for (int c = 0; c < 8; ++c) bv[c] = *(const uint2*)(tb + c * 64 + pht);
#pragma unroll
    for (int r = 0; r < 8; ++r) {
      h2 alo = bch2(av[r].x), ahi = bch2(av[r].y);
#pragma unroll
      for (int c = 0; c < 8; ++c) {
        acc[r][c] = fdot2f(alo, bch2(bv[c].x), acc[r][c]);
        acc[r][c] = fdot2f(ahi, bch2(bv[c].y), acc[r][c]);
      }
    }
  }
}

// ---------------- Phase A: per-block min/max of sq (pre-sqrt, monotone) -------------
__global__ __launch_bounds__(256, 2) void phaseA(const float* __restrict__ eeg,
                                                 const float* __restrict__ text,
                                                 float* __restrict__ ws) {
  extern __shared__ char smem[];
  uint32_t* eL = (uint32_t*)smem;              // 32768 B
  uint32_t* tL = (uint32_t*)(smem + 32768);    // 32768 B
  float* e2a   = (float*)(smem + 65536);       // 512 B
  float* t2a   = (float*)(smem + 66048);       // 512 B
  float* red   = (float*)(smem + 66560);       // 32 B
  int t = threadIdx.x, b = blockIdx.x;
  const float* ep = eeg + (size_t)(b >> 6) * 16384;
  const float* tp = text + (size_t)(b & 63) * 16384;

  stage2(ep, tp, eL, tL, t);
  __syncthreads();
  {
    int r = t & 127;
    const uint32_t* base = ((t < 128) ? eL : tL) + r * 64;
    float nn = norm2of(base, ((r >> 3) & 7) << 2);
    if (t < 128) e2a[r] = nn; else t2a[r] = nn;
  }
  __syncthreads();

  int rg = t >> 4, cg = t & 15;
  float acc[8][8];
#pragma unroll
  for (int r = 0; r < 8; ++r)
#pragma unroll
    for (int c = 0; c < 8; ++c) acc[r][c] = 0.f;
  build8x8(eL, tL, rg, cg, acc);

  float e2r[8], t2c[8];
#pragma unroll
  for (int r = 0; r < 8; ++r) e2r[r] = e2a[8 * rg + r];
#pragma unroll
  for (int c = 0; c < 8; ++c) t2c[c] = t2a[8 * cg + c];

  float smn = 1e30f, smx = -1e30f;
#pragma unroll
  for (int r = 0; r < 8; ++r)
#pragma unroll
    for (int c = 0; c < 8; ++c) {
      float ip = rnd16(acc[r][c]);
      float sq = fmaxf(fmaf(-2.0f, ip, e2r[r] + t2c[c]), 0.0f);
      smn = fminf(smn, sq);
      smx = fmaxf(smx, sq);
    }
#pragma unroll
  for (int msk = 1; msk < 64; msk <<= 1) {
    smn = fminf(smn, __shfl_xor(smn, msk));
    smx = fmaxf(smx, __shfl_xor(smx, msk));
  }
  if ((t & 63) == 0) { red[t >> 6] = smn; red[4 + (t >> 6)] = smx; }
  __syncthreads();
  if (t == 0) {
    float mn = fminf(fminf(red[0], red[1]), fminf(red[2], red[3]));
    float mx = fmaxf(fmaxf(red[4], red[5]), fmaxf(red[6], red[7]));
    ws[2 + 2 * b] = mn;
    ws[3 + 2 * b] = mx;
  }
}

// ---------------- Phase B: reduce 4096 block min/max -> cost_min, cost_span ---------
__global__ void phaseB(float* __restrict__ ws) {
  __shared__ float red[16];
  int t = threadIdx.x;
  float mn = 1e30f, mx = -1e30f;
#pragma unroll
  for (int k = 0; k < 16; ++k) {
    int idx = k * 256 + t;
    mn = fminf(mn, ws[2 + 2 * idx]);
    mx = fmaxf(mx, ws[3 + 2 * idx]);
  }
#pragma unroll
  for (int msk = 1; msk < 64; msk <<= 1) {
    mn = fminf(mn, __shfl_xor(mn, msk));
    mx = fmaxf(mx, __shfl_xor(mx, msk));
  }
  if ((t & 63) == 0) { red[t >> 6] = mn; red[8 + (t >> 6)] = mx; }
  __syncthreads();
  if (t == 0) {
    mn = fminf(fminf(red[0], red[1]), fminf(red[2], red[3]));
    mx = fmaxf(fmaxf(red[8], red[9]), fmaxf(red[10], red[11]));
    float cmn = rnd16(sqrtf(rnd16(mn)));
    float cmx = rnd16(sqrtf(rnd16(mx)));
    ws[0] = cmn;
    ws[1] = cmx - cmn;
  }
}

// ---------------- Phase C: register-resident Sinkhorn ------------------------------
// K' = 2^8 * exp(-(c-cmn)/(0.1*span)) stored fp16 (all values normal: [0.0116,256]).
// Per lane: kk = K rows {n0,n0+1} x 32 cols (col-paired h2), kt = K cols {c0,c1} x 32
// rows (row-paired h2). u/v exchanged via 256B fp16 LDS vectors; fp32 in-register.
__global__ __launch_bounds__(256, 2) void phaseC(const float* __restrict__ eeg,
                                                 const float* __restrict__ text,
                                                 float* __restrict__ ws) {
  extern __shared__ char smem[];
  uint32_t* eL  = (uint32_t*)smem;              // staging (32KB); later K_h2
  uint32_t* tL  = (uint32_t*)(smem + 32768);    // 32KB
  uint32_t* Kh  = (uint32_t*)smem;              // K_h2 overlay (32KB)
  float* e2a    = (float*)(smem + 65536);       // 512 B
  float* t2a    = (float*)(smem + 66048);       // 512 B
  uint32_t* vh2 = (uint32_t*)(smem + 66560);    // 256 B (64 h2-pairs)
  uint32_t* uh2 = (uint32_t*)(smem + 66816);    // 256 B
  float* red    = (float*)(smem + 67072);       // 32 B -> total 67104
  int t = threadIdx.x, b = blockIdx.x;
  const float* ep = eeg + (size_t)(b >> 6) * 16384;
  const float* tp = text + (size_t)(b & 63) * 16384;

  stage2(ep, tp, eL, tL, t);
  __syncthreads();
  {
    int r = t & 127;
    const uint32_t* base = ((t < 128) ? eL : tL) + r * 64;
    float nn = norm2of(base, ((r >> 3) & 7) << 2);
    if (t < 128) e2a[r] = nn; else t2a[r] = nn;
  }
  __syncthreads();

  int rg = t >> 4, cg = t & 15;
  float acc[8][8];
#pragma unroll
  for (int r = 0; r < 8; ++r)
#pragma unroll
    for (int c = 0; c < 8; ++c) acc[r][c] = 0.f;
  build8x8(eL, tL, rg, cg, acc);

  float cmn = ws[0];
  float kexp2 = 1.4426950408889634f / (0.1f * ws[1]);  // log2e/(reg*span)

  float e2r[8], t2c[8];
#pragma unroll
  for (int r = 0; r < 8; ++r) e2r[r] = e2a[8 * rg + r];
#pragma unroll
  for (int c = 0; c < 8; ++c) t2c[c] = t2a[8 * cg + c];

  float ks = 0.f;
  uint32_t kw[8][4];
#pragma unroll
  for (int r = 0; r < 8; ++r)
#pragma unroll
    for (int c2 = 0; c2 < 4; ++c2) {
      float ip0 = rnd16(acc[r][2 * c2]);
      float ip1 = rnd16(acc[r][2 * c2 + 1]);
      float sq0 = fmaxf(fmaf(-2.0f, ip0, e2r[r] + t2c[2 * c2]), 0.0f);
      float sq1 = fmaxf(fmaf(-2.0f, ip1, e2r[r] + t2c[2 * c2 + 1]), 0.0f);
      float c0 = rnd16(sqrtf(rnd16(sq0)));
      float c1 = rnd16(sqrtf(rnd16(sq1)));
      float k0 = exp2f(fmaf(cmn - c0, kexp2, 8.0f));   // 2^8-scaled kernel
      float k1 = exp2f(fmaf(cmn - c1, kexp2, 8.0f));
      ks += k0 + k1;
      kw[r][c2] = pkh2(k0, k1);
    }
  __syncthreads();   // all build reads of eL done before K_h2 overlay writes

  // K_h2[row][hc] at row*64 + ((hc>>2 + row>>1)&15)*4 + (hc&3)  (rotation swizzle)
#pragma unroll
  for (int r = 0; r < 8; ++r) {
    int row = 8 * rg + r, rh = row >> 1;
#pragma unroll
    for (int c2 = 0; c2 < 4; ++c2)
      Kh[row * 64 + (((cg + rh) & 15) * 4 + c2)] = kw[r][c2];
  }
#pragma unroll
  for (int msk = 1; msk < 64; msk <<= 1) ks += __shfl_xor(ks, msk);
  if ((t & 63) == 0) red[t >> 6] = ks;
  __syncthreads();
  float Sp = (red[0] + red[1]) + (red[2] + red[3]);   // = 256 * sum(K)
  float u0 = 256.0f / Sp;                              // = 1/sum(K)
  if (t < 64) { vh2[t] = 0x3C003C00u; uh2[t] = pkh2(u0, u0); }

  // Load register tiles (K_h2 writes are sync'd above).
  int l = t & 63, w = t >> 6, a = l >> 2, bq = l & 3;
  int n0 = 32 * w + 2 * a;       // my 2 rows
  int nh = 16 * w + a;           // = n0>>1 ; also my col-pair index
  uint32_t kk0[16], kk1[16], kt0[16], kt1[16];
#pragma unroll
  for (int q = 0; q < 4; ++q) {
    int grp = (4 * bq + q + nh) & 15;
    uint4 x0 = *(const uint4*)(Kh + n0 * 64 + grp * 4);
    uint4 x1 = *(const uint4*)(Kh + (n0 + 1) * 64 + grp * 4);
    kk0[4 * q] = x0.x; kk0[4 * q + 1] = x0.y; kk0[4 * q + 2] = x0.z; kk0[4 * q + 3] = x0.w;
    kk1[4 * q] = x1.x; kk1[4 * q + 1] = x1.y; kk1[4 * q + 2] = x1.z; kk1[4 * q + 3] = x1.w;
  }
  int cgk = nh >> 2, pos = a & 3;
#pragma unroll
  for (int k = 0; k < 16; ++k) {
    int r0 = 32 * bq + 2 * k;
    int rh = 16 * bq + k;        // r0>>1 == (r0+1)>>1
    uint32_t v0 = Kh[r0 * 64 + (((cgk + rh) & 15) * 4 + pos)];
    uint32_t v1 = Kh[(r0 + 1) * 64 + (((cgk + rh) & 15) * 4 + pos)];
    kt0[k] = __builtin_amdgcn_perm(v1, v0, 0x05040100u);  // (lo,lo): col c0, row-pair
    kt1[k] = __builtin_amdgcn_perm(v1, v0, 0x07060302u);  // (hi,hi): col c1
  }
  __syncthreads();   // uh2/vh2 init visible

  float uf0 = u0, uf1 = u0, vf0 = 1.0f, vf1 = 1.0f;

  for (int it = 0; it < 100; ++it) {
    // row sweep: w = K v ; u <- u / (u*w + 1e-8)
    uint32_t vh[16];
#pragma unroll
    for (int q = 0; q < 4; ++q) {
      uint4 x = *(const uint4*)(vh2 + 16 * bq + 4 * q);
      vh[4 * q] = x.x; vh[4 * q + 1] = x.y; vh[4 * q + 2] = x.z; vh[4 * q + 3] = x.w;
    }
    float w0 = 0.f, w1 = 0.f;
#pragma unroll
    for (int k = 0; k < 16; ++k) {
      w0 = fdot2f(bch2(kk0[k]), bch2(vh[k]), w0);
      w1 = fdot2f(bch2(kk1[k]), bch2(vh[k]), w1);
    }
    w0 += __shfl_xor(w0, 1); w0 += __shfl_xor(w0, 2);
    w1 += __shfl_xor(w1, 1); w1 += __shfl_xor(w1, 2);
    float d0 = fmaf(uf0, w0 * 0x1p-8f, 1e-8f);
    float d1 = fmaf(uf1, w1 * 0x1p-8f, 1e-8f);
    uf0 = uf0 * __builtin_amdgcn_rcpf(d0);
    uf1 = uf1 * __builtin_amdgcn_rcpf(d1);
    if (bq == 0) uh2[nh] = pkh2(uf0, uf1);
    __syncthreads();

    // col sweep: z = K^T u ; v <- v / (v*z + 1e-8)
    uint32_t uh[16];
#pragma unroll
    for (int q = 0; q < 4; ++q) {
      uint4 x = *(const uint4*)(uh2 + 16 * bq + 4 * q);
      uh[4 * q] = x.x; uh[4 * q + 1] = x.y; uh[4 * q + 2] = x.z; uh[4 * q + 3] = x.w;
    }
    float z0 = 0.f, z1 = 0.f;
#pragma unroll
    for (int k = 0; k < 16; ++k) {
      z0 = fdot2f(bch2(kt0[k]), bch2(uh[k]), z0);
      z1 = fdot2f(bch2(kt1[k]), bch2(uh[k]), z1);
    }
    z0 += __shfl_xor(z0, 1); z0 += __shfl_xor(z0, 2);
    z1 += __shfl_xor(z1, 1); z1 += __shfl_xor(z1, 2);
    float e0 = fmaf(vf0, z0 * 0x1p-8f, 1e-8f);
    float e1 = fmaf(vf1, z1 * 0x1p-8f, 1e-8f);
    vf0 = vf0 * __builtin_amdgcn_rcpf(e0);
    vf1 = vf1 * __builtin_amdgcn_rcpf(e1);
    if (bq == 0) vh2[nh] = pkh2(vf0, vf1);
    __syncthreads();
  }

  // distance = sum u K v * cost_n ; cost_n = 0.1*ln2*(8 - log2(K'))
  {
    uint32_t vh[16];
#pragma unroll
    for (int q = 0; q < 4; ++q) {
      uint4 x = *(const uint4*)(vh2 + 16 * bq + 4 * q);
      vh[4 * q] = x.x; vh[4 * q + 1] = x.y; vh[4 * q + 2] = x.z; vh[4 * q + 3] = x.w;
    }
    float acc0 = 0.f, acc1 = 0.f;
#pragma unroll
    for (int k = 0; k < 16; ++k) {
      h2 vp = bch2(vh[k]);
      h2 k0 = bch2(kk0[k]);
      h2 k1 = bch2(kk1[k]);
      float kf, vf;
      kf = (float)k0[0]; vf = (float)vp[0]; acc0 += kf * vf * (8.0f - __log2f(kf));
      kf = (float)k0[1]; vf = (float)vp[1]; acc0 += kf * vf * (8.0f - __log2f(kf));
      kf = (float)k1[0]; vf = (float)vp[0]; acc1 += kf * vf * (8.0f - __log2f(kf));
      kf = (float)k1[1]; vf = (float)vp[1]; acc1 += kf * vf * (8.0f - __log2f(kf));
    }
    float tot = (uf0 * acc0 + uf1 * acc1) * (0.069314718055994531f * 0x1p-8f);
#pragma unroll
    for (int msk = 1; msk < 64; msk <<= 1) tot += __shfl_xor(tot, msk);
    if (l == 0) red[w] = tot;
    __syncthreads();
    if (t == 0) ws[8194 + b] = (red[0] + red[1]) + (red[2] + red[3]);
  }
}

// ---------------- Phase D: minmax(d) -> similarity -> CE loss ------------------------
__global__ void phaseD(const float* __restrict__ ws, float* __restrict__ out) {
  __shared__ float sim[4096];
  __shared__ float red[16];
  int t = threadIdx.x;
  const float* d = ws + 8194;
  float dv[16];
  float mn = 1e30f, mx = -1e30f;
#pragma unroll
  for (int k = 0; k < 16; ++k) {
    dv[k] = d[k * 256 + t];
    mn = fminf(mn, dv[k]);
    mx = fmaxf(mx, dv[k]);
  }
#pragma unroll
  for (int msk = 1; msk < 64; msk <<= 1) {
    mn = fminf(mn, __shfl_xor(mn, msk));
    mx = fmaxf(mx, __shfl_xor(mx, msk));
  }
  if ((t & 63) == 0) { red[t >> 6] = mn; red[8 + (t >> 6)] = mx; }
  __syncthreads();
  mn = fminf(fminf(red[0], red[1]), fminf(red[2], red[3]));
  mx = fmaxf(fmaxf(red[8], red[9]), fmaxf(red[10], red[11]));
  float inv = 1.0f / (mx - mn);
#pragma unroll
  for (int k = 0; k < 16; ++k) {
    int idx = k * 256 + t;
    float s = expf(-(dv[k] - mn) * inv);
    sim[idx] = s;
    out[1 + idx] = s;
  }
  __syncthreads();
  if (t < 64) {
    float a = 0.f;
    for (int j = 0; j < 64; ++j) a += expf(sim[t * 64 + j]);
    float val = logf(a) - sim[t * 64 + t];
#pragma unroll
    for (int msk = 1; msk < 64; msk <<= 1) val += __shfl_xor(val, msk);
    if (t == 0) out[0] = val * (1.0f / 64.0f);
  }
}

extern "C" void kernel_launch(void* const* d_in, const int* in_sizes, int n_in,
                              void* d_out, int out_size, void* d_ws, size_t ws_size,
                              hipStream_t stream) {
  const float* eeg  = (const float*)d_in[0];
  const float* text = (const float*)d_in[1];
  float* out = (float*)d_out;
  float* ws  = (float*)d_ws;   // needs 12290 floats = 49160 B

  phaseA<<<4096, 256, 66592, stream>>>(eeg, text, ws);
  phaseB<<<1, 256, 0, stream>>>(ws);
  phaseC<<<4096, 256, 67104, stream>>>(eeg, text, ws);
  phaseD<<<1, 256, 0, stream>>>(ws, out);
}

// Round 3
// 733.545 us; speedup vs baseline: 2.6530x; 1.2683x over previous
//
#include <hip/hip_runtime.h>
#include <stdint.h>
#include <math.h>

// OptimalTransportLoss: b=64 pairs^2, n=128, d=128.
// ws floats: [0]=cost_min, [1]=cost_span, [2..8193]=per-block sq min/max pairs,
//            [8194..12289]=distances per (i,j) block.
//
// LDS layout (bytes), 34336 total:
//   [0,16384)      eL: e-half, 128 rows x 32 u32 (fp16 pairs)   } overlaid by
//   [16384,32768)  tL: t-half                                   } Kh (8192 u32)
//   [32768,33280)  e2a (128 f32)
//   [33280,33792)  t2a (128 f32)
//   [33792,34048)  vh2 (64 u32 = 128 fp16)
//   [34048,34304)  uh2
//   [34304,34336)  red (8 f32)

typedef _Float16 h2 __attribute__((ext_vector_type(2)));

__device__ __forceinline__ h2 bch2(uint32_t u) { return __builtin_bit_cast(h2, u); }
__device__ __forceinline__ uint32_t pkh2(float x, float y) {
  h2 h = {(_Float16)x, (_Float16)y};
  return __builtin_bit_cast(uint32_t, h);
}
__device__ __forceinline__ float rnd16(float x) { return (float)(_Float16)x; }
__device__ __forceinline__ float fdot2f(h2 a, h2 b, float c) {
  return __builtin_amdgcn_fdot2(a, b, c, false);
}

// Stage d-half p (cols 64p..64p+63) of eeg[i], text[j] into LDS as fp16 pairs.
// Row m, local u32 j stored at m*32 + (j ^ (((m>>3)&7)<<2)).
__device__ __forceinline__ void stageHalf(const float* __restrict__ ep,
                                          const float* __restrict__ tp,
                                          uint32_t* eL, uint32_t* tL, int t, int p) {
  const float4* e4 = (const float4*)ep;
  const float4* t4 = (const float4*)tp;
#pragma unroll
  for (int k = 0; k < 8; ++k) {
    int F = k * 256 + t;          // 0..2047
    int m = F >> 4, g = F & 15;   // row, float4-group within half
    int src = m * 32 + 16 * p + g;
    int idx = m * 32 + ((2 * g) ^ (((m >> 3) & 7) << 2));  // even; +1 adjacent
    float4 x = e4[src];
    *(uint2*)(eL + idx) = make_uint2(pkh2(x.x, x.y), pkh2(x.z, x.w));
    float4 y = t4[src];
    *(uint2*)(tL + idx) = make_uint2(pkh2(y.x, y.y), pkh2(y.z, y.w));
  }
}

// Accumulate fp16 squared-norm partial for this thread's row over one half.
__device__ __forceinline__ void normPartial(const uint32_t* eL, const uint32_t* tL,
                                            int t, float& a0, float& a1) {
  int r = t & 127;
  const uint32_t* base = ((t < 128) ? eL : tL) + r * 32;
  int sw = ((r >> 3) & 7) << 2;
#pragma unroll
  for (int kl = 0; kl < 16; ++kl) {
    uint2 u = *(const uint2*)(base + ((2 * kl) ^ sw));
    h2 x = bch2(u.x), y = bch2(u.y);
    a0 = fdot2f(x, x, a0);
    a1 = fdot2f(y, y, a1);
  }
}

// 8x8 register-tiled inner products over one d-half (16 kp steps).
__device__ __forceinline__ void buildPass(const uint32_t* eL, const uint32_t* tL,
                                          int rg, int cg, float (&acc)[8][8]) {
  const uint32_t* eb = eL + rg * 256;
  const uint32_t* tb = tL + cg * 256;
  int swe = (rg & 7) << 2, swt = (cg & 7) << 2;
#pragma unroll 4
  for (int kp = 0; kp < 16; ++kp) {
    int phe = (2 * kp) ^ swe, pht = (2 * kp) ^ swt;
    uint2 av[8], bv[8];
#pragma unroll
    for (int r = 0; r < 8; ++r) av[r] = *(const uint2*)(eb + r * 32 + phe);
#pragma unroll
    for (int c = 0; c < 8; ++c) bv[c] = *(const uint2*)(tb + c * 32 + pht);
#pragma unroll
    for (int r = 0; r < 8; ++r) {
      h2 alo = bch2(av[r].x), ahi = bch2(av[r].y);
#pragma unroll
      for (int c = 0; c < 8; ++c) {
        acc[r][c] = fdot2f(alo, bch2(bv[c].x), acc[r][c]);
        acc[r][c] = fdot2f(ahi, bch2(bv[c].y), acc[r][c]);
      }
    }
  }
}

// ---------------- Phase A: per-block min/max of sq (pre-sqrt, monotone) -------------
__global__ __launch_bounds__(256, 4) void phaseA(const float* __restrict__ eeg,
                                                 const float* __restrict__ text,
                                                 float* __restrict__ ws) {
  extern __shared__ char smem[];
  uint32_t* eL = (uint32_t*)smem;
  uint32_t* tL = (uint32_t*)(smem + 16384);
  float* e2a   = (float*)(smem + 32768);
  float* t2a   = (float*)(smem + 33280);
  float* red   = (float*)(smem + 34304);
  int t = threadIdx.x, b = blockIdx.x;
  const float* ep = eeg + (size_t)(b >> 6) * 16384;
  const float* tp = text + (size_t)(b & 63) * 16384;

  int rg = t >> 4, cg = t & 15;
  float acc[8][8];
#pragma unroll
  for (int r = 0; r < 8; ++r)
#pragma unroll
    for (int c = 0; c < 8; ++c) acc[r][c] = 0.f;
  float na0 = 0.f, na1 = 0.f;

  stageHalf(ep, tp, eL, tL, t, 0);
  __syncthreads();
  normPartial(eL, tL, t, na0, na1);
  buildPass(eL, tL, rg, cg, acc);
  __syncthreads();
  stageHalf(ep, tp, eL, tL, t, 1);
  __syncthreads();
  normPartial(eL, tL, t, na0, na1);
  {
    int r = t & 127;
    float nn = rnd16(na0 + na1);
    if (t < 128) e2a[r] = nn; else t2a[r] = nn;
  }
  buildPass(eL, tL, rg, cg, acc);
  __syncthreads();

  float e2r[8], t2c[8];
#pragma unroll
  for (int r = 0; r < 8; ++r) e2r[r] = e2a[8 * rg + r];
#pragma unroll
  for (int c = 0; c < 8; ++c) t2c[c] = t2a[8 * cg + c];

  float smn = 1e30f, smx = -1e30f;
#pragma unroll
  for (int r = 0; r < 8; ++r)
#pragma unroll
    for (int c = 0; c < 8; ++c) {
      float ip = rnd16(acc[r][c]);
      float sq = fmaxf(fmaf(-2.0f, ip, e2r[r] + t2c[c]), 0.0f);
      smn = fminf(smn, sq);
      smx = fmaxf(smx, sq);
    }
#pragma unroll
  for (int msk = 1; msk < 64; msk <<= 1) {
    smn = fminf(smn, __shfl_xor(smn, msk));
    smx = fmaxf(smx, __shfl_xor(smx, msk));
  }
  if ((t & 63) == 0) { red[t >> 6] = smn; red[4 + (t >> 6)] = smx; }
  __syncthreads();
  if (t == 0) {
    float mn = fminf(fminf(red[0], red[1]), fminf(red[2], red[3]));
    float mx = fmaxf(fmaxf(red[4], red[5]), fmaxf(red[6], red[7]));
    ws[2 + 2 * b] = mn;
    ws[3 + 2 * b] = mx;
  }
}

// ---------------- Phase B: reduce 4096 block min/max -> cost_min, cost_span ---------
__global__ void phaseB(float* __restrict__ ws) {
  __shared__ float red[16];
  int t = threadIdx.x;
  float mn = 1e30f, mx = -1e30f;
#pragma unroll
  for (int k = 0; k < 16; ++k) {
    int idx = k * 256 + t;
    mn = fminf(mn, ws[2 + 2 * idx]);
    mx = fmaxf(mx, ws[3 + 2 * idx]);
  }
#pragma unroll
  for (int msk = 1; msk < 64; msk <<= 1) {
    mn = fminf(mn, __shfl_xor(mn, msk));
    mx = fmaxf(mx, __shfl_xor(mx, msk));
  }
  if ((t & 63) == 0) { red[t >> 6] = mn; red[8 + (t >> 6)] = mx; }
  __syncthreads();
  if (t == 0) {
    mn = fminf(fminf(red[0], red[1]), fminf(red[2], red[3]));
    mx = fmaxf(fmaxf(red[8], red[9]), fmaxf(red[10], red[11]));
    float cmn = rnd16(sqrtf(rnd16(mn)));
    float cmx = rnd16(sqrtf(rnd16(mx)));
    ws[0] = cmn;
    ws[1] = cmx - cmn;
  }
}

// ---------------- Phase C: register-resident Sinkhorn ------------------------------
// K' = 2^8 * exp(-(c-cmn)/(0.1*span)) stored fp16 (all values normal: [0.0116,256]).
__global__ __launch_bounds__(256, 4) void phaseC(const float* __restrict__ eeg,
                                                 const float* __restrict__ text,
                                                 float* __restrict__ ws) {
  extern __shared__ char smem[];
  uint32_t* eL  = (uint32_t*)smem;
  uint32_t* tL  = (uint32_t*)(smem + 16384);
  uint32_t* Kh  = (uint32_t*)smem;              // 8192 u32 overlay
  float* e2a    = (float*)(smem + 32768);
  float* t2a    = (float*)(smem + 33280);
  uint32_t* vh2 = (uint32_t*)(smem + 33792);
  uint32_t* uh2 = (uint32_t*)(smem + 34048);
  float* red    = (float*)(smem + 34304);
  int t = threadIdx.x, b = blockIdx.x;
  const float* ep = eeg + (size_t)(b >> 6) * 16384;
  const float* tp = text + (size_t)(b & 63) * 16384;

  int rg = t >> 4, cg = t & 15;
  float acc[8][8];
#pragma unroll
  for (int r = 0; r < 8; ++r)
#pragma unroll
    for (int c = 0; c < 8; ++c) acc[r][c] = 0.f;
  float na0 = 0.f, na1 = 0.f;

  stageHalf(ep, tp, eL, tL, t, 0);
  __syncthreads();
  normPartial(eL, tL, t, na0, na1);
  buildPass(eL, tL, rg, cg, acc);
  __syncthreads();
  stageHalf(ep, tp, eL, tL, t, 1);
  __syncthreads();
  normPartial(eL, tL, t, na0, na1);
  {
    int r = t & 127;
    float nn = rnd16(na0 + na1);
    if (t < 128) e2a[r] = nn; else t2a[r] = nn;
  }
  buildPass(eL, tL, rg, cg, acc);
  __syncthreads();   // eL/tL reads done; e2a/t2a visible; Kh overlay now safe

  float cmn = ws[0];
  float kexp2 = 1.4426950408889634f / (0.1f * ws[1]);  // log2e/(reg*span)

  float e2r[8], t2c[8];
#pragma unroll
  for (int r = 0; r < 8; ++r) e2r[r] = e2a[8 * rg + r];
#pragma unroll
  for (int c = 0; c < 8; ++c) t2c[c] = t2a[8 * cg + c];

  float ks = 0.f;
#pragma unroll
  for (int r = 0; r < 8; ++r) {
    int row = 8 * rg + r, rh = row >> 1;
    uint32_t kw[4];
#pragma unroll
    for (int c2 = 0; c2 < 4; ++c2) {
      float ip0 = rnd16(acc[r][2 * c2]);
      float ip1 = rnd16(acc[r][2 * c2 + 1]);
      float sq0 = fmaxf(fmaf(-2.0f, ip0, e2r[r] + t2c[2 * c2]), 0.0f);
      float sq1 = fmaxf(fmaf(-2.0f, ip1, e2r[r] + t2c[2 * c2 + 1]), 0.0f);
      float c0 = rnd16(sqrtf(rnd16(sq0)));
      float c1 = rnd16(sqrtf(rnd16(sq1)));
      float k0 = exp2f(fmaf(cmn - c0, kexp2, 8.0f));   // 2^8-scaled kernel
      float k1 = exp2f(fmaf(cmn - c1, kexp2, 8.0f));
      ks += k0 + k1;
      kw[c2] = pkh2(k0, k1);
    }
    // rotation swizzle: h2 col hc at row*64 + ((hc>>2 + rh)&15)*4 + (hc&3)
#pragma unroll
    for (int c2 = 0; c2 < 4; ++c2)
      Kh[row * 64 + (((cg + rh) & 15) * 4 + c2)] = kw[c2];
  }
#pragma unroll
  for (int msk = 1; msk < 64; msk <<= 1) ks += __shfl_xor(ks, msk);
  if ((t & 63) == 0) red[t >> 6] = ks;
  __syncthreads();
  float Sp = (red[0] + red[1]) + (red[2] + red[3]);   // = 256 * sum(K)
  float u0 = 256.0f / Sp;                              // = 1/sum(K)
  if (t < 64) { vh2[t] = 0x3C003C00u; uh2[t] = pkh2(u0, u0); }

  // Register tiles: lane (w,a,bq): rows n0,n0+1 (kk0/kk1), cols 2nh,2nh+1 (kt0/kt1).
  int l = t & 63, w = t >> 6, a = l >> 2, bq = l & 3;
  int n0 = 32 * w + 2 * a;
  int nh = 16 * w + a;
  uint32_t kk0[16], kk1[16], kt0[16], kt1[16];
#pragma unroll
  for (int q = 0; q < 4; ++q) {
    int grp = (4 * bq + q + nh) & 15;
    uint4 x0 = *(const uint4*)(Kh + n0 * 64 + grp * 4);
    uint4 x1 = *(const uint4*)(Kh + (n0 + 1) * 64 + grp * 4);
    kk0[4 * q] = x0.x; kk0[4 * q + 1] = x0.y; kk0[4 * q + 2] = x0.z; kk0[4 * q + 3] = x0.w;
    kk1[4 * q] = x1.x; kk1[4 * q + 1] = x1.y; kk1[4 * q + 2] = x1.z; kk1[4 * q + 3] = x1.w;
  }
  int cgk = nh >> 2, pos = a & 3;
#pragma unroll
  for (int k = 0; k < 16; ++k) {
    int r0 = 32 * bq + 2 * k;
    int rh = 16 * bq + k;
    uint32_t v0 = Kh[r0 * 64 + (((cgk + rh) & 15) * 4 + pos)];
    uint32_t v1 = Kh[(r0 + 1) * 64 + (((cgk + rh) & 15) * 4 + pos)];
    kt0[k] = __builtin_amdgcn_perm(v1, v0, 0x05040100u);  // (lo,lo): col 2nh
    kt1[k] = __builtin_amdgcn_perm(v1, v0, 0x07060302u);  // (hi,hi): col 2nh+1
  }
  __syncthreads();   // uh2/vh2 init visible

  float uf0 = u0, uf1 = u0, vf0 = 1.0f, vf1 = 1.0f;

  for (int it = 0; it < 100; ++it) {
    // row sweep: w = K v ; u <- u / (u*w + 1e-8)
    uint32_t vh[16];
#pragma unroll
    for (int q = 0; q < 4; ++q) {
      uint4 x = *(const uint4*)(vh2 + 16 * bq + 4 * q);
      vh[4 * q] = x.x; vh[4 * q + 1] = x.y; vh[4 * q + 2] = x.z; vh[4 * q + 3] = x.w;
    }
    float w0a = 0.f, w0b = 0.f, w1a = 0.f, w1b = 0.f;
#pragma unroll
    for (int k = 0; k < 8; ++k) {
      w0a = fdot2f(bch2(kk0[k]),     bch2(vh[k]),     w0a);
      w0b = fdot2f(bch2(kk0[k + 8]), bch2(vh[k + 8]), w0b);
      w1a = fdot2f(bch2(kk1[k]),     bch2(vh[k]),     w1a);
      w1b = fdot2f(bch2(kk1[k + 8]), bch2(vh[k + 8]), w1b);
    }
    float w0 = w0a + w0b, w1 = w1a + w1b;
    w0 += __shfl_xor(w0, 1); w0 += __shfl_xor(w0, 2);
    w1 += __shfl_xor(w1, 1); w1 += __shfl_xor(w1, 2);
    float d0 = fmaf(uf0, w0 * 0x1p-8f, 1e-8f);
    float d1 = fmaf(uf1, w1 * 0x1p-8f, 1e-8f);
    uf0 = uf0 * __builtin_amdgcn_rcpf(d0);
    uf1 = uf1 * __builtin_amdgcn_rcpf(d1);
    if (bq == 0) uh2[nh] = pkh2(uf0, uf1);
    __syncthreads();

    // col sweep: z = K^T u ; v <- v / (v*z + 1e-8)
    uint32_t uh[16];
#pragma unroll
    for (int q = 0; q < 4; ++q) {
      uint4 x = *(const uint4*)(uh2 + 16 * bq + 4 * q);
      uh[4 * q] = x.x; uh[4 * q + 1] = x.y; uh[4 * q + 2] = x.z; uh[4 * q + 3] = x.w;
    }
    float z0a = 0.f, z0b = 0.f, z1a = 0.f, z1b = 0.f;
#pragma unroll
    for (int k = 0; k < 8; ++k) {
      z0a = fdot2f(bch2(kt0[k]),     bch2(uh[k]),     z0a);
      z0b = fdot2f(bch2(kt0[k + 8]), bch2(uh[k + 8]), z0b);
      z1a = fdot2f(bch2(kt1[k]),     bch2(uh[k]),     z1a);
      z1b = fdot2f(bch2(kt1[k + 8]), bch2(uh[k + 8]), z1b);
    }
    float z0 = z0a + z0b, z1 = z1a + z1b;
    z0 += __shfl_xor(z0, 1); z0 += __shfl_xor(z0, 2);
    z1 += __shfl_xor(z1, 1); z1 += __shfl_xor(z1, 2);
    float e0 = fmaf(vf0, z0 * 0x1p-8f, 1e-8f);
    float e1 = fmaf(vf1, z1 * 0x1p-8f, 1e-8f);
    vf0 = vf0 * __builtin_amdgcn_rcpf(e0);
    vf1 = vf1 * __builtin_amdgcn_rcpf(e1);
    if (bq == 0) vh2[nh] = pkh2(vf0, vf1);
    __syncthreads();
  }

  // distance = sum u K v * cost_n ; cost_n = 0.1*ln2*(8 - log2(K'))
  {
    uint32_t vh[16];
#pragma unroll
    for (int q = 0; q < 4; ++q) {
      uint4 x = *(const uint4*)(vh2 + 16 * bq + 4 * q);
      vh[4 * q] = x.x; vh[4 * q + 1] = x.y; vh[4 * q + 2] = x.z; vh[4 * q + 3] = x.w;
    }
    float acc0 = 0.f, acc1 = 0.f;
#pragma unroll
    for (int k = 0; k < 16; ++k) {
      h2 vp = bch2(vh[k]);
      h2 k0 = bch2(kk0[k]);
      h2 k1 = bch2(kk1[k]);
      float kf, vf;
      kf = (float)k0[0]; vf = (float)vp[0]; acc0 += kf * vf * (8.0f - __log2f(kf));
      kf = (float)k0[1]; vf = (float)vp[1]; acc0 += kf * vf * (8.0f - __log2f(kf));
      kf = (float)k1[0]; vf = (float)vp[0]; acc1 += kf * vf * (8.0f - __log2f(kf));
      kf = (float)k1[1]; vf = (float)vp[1]; acc1 += kf * vf * (8.0f - __log2f(kf));
    }
    float tot = (uf0 * acc0 + uf1 * acc1) * (0.069314718055994531f * 0x1p-8f);
#pragma unroll
    for (int msk = 1; msk < 64; msk <<= 1) tot += __shfl_xor(tot, msk);
    if (l == 0) red[w] = tot;
    __syncthreads();
    if (t == 0) ws[8194 + b] = (red[0] + red[1]) + (red[2] + red[3]);
  }
}

// ---------------- Phase D: minmax(d) -> similarity -> CE loss ------------------------
__global__ void phaseD(const float* __restrict__ ws, float* __restrict__ out) {
  __shared__ float sim[4096];
  __shared__ float red[16];
  int t = threadIdx.x;
  const float* d = ws + 8194;
  float dv[16];
  float mn = 1e30f, mx = -1e30f;
#pragma unroll
  for (int k = 0; k < 16; ++k) {
    dv[k] = d[k * 256 + t];
    mn = fminf(mn, dv[k]);
    mx = fmaxf(mx, dv[k]);
  }
#pragma unroll
  for (int msk = 1; msk < 64; msk <<= 1) {
    mn = fminf(mn, __shfl_xor(mn, msk));
    mx = fmaxf(mx, __shfl_xor(mx, msk));
  }
  if ((t & 63) == 0) { red[t >> 6] = mn; red[8 + (t >> 6)] = mx; }
  __syncthreads();
  mn = fminf(fminf(red[0], red[1]), fminf(red[2], red[3]));
  mx = fmaxf(fmaxf(red[8], red[9]), fmaxf(red[10], red[11]));
  float inv = 1.0f / (mx - mn);
#pragma unroll
  for (int k = 0; k < 16; ++k) {
    int idx = k * 256 + t;
    float s = expf(-(dv[k] - mn) * inv);
    sim[idx] = s;
    out[1 + idx] = s;
  }
  __syncthreads();
  if (t < 64) {
    float a = 0.f;
    for (int j = 0; j < 64; ++j) a += expf(sim[t * 64 + j]);
    float val = logf(a) - sim[t * 64 + t];
#pragma unroll
    for (int msk = 1; msk < 64; msk <<= 1) val += __shfl_xor(val, msk);
    if (t == 0) out[0] = val * (1.0f / 64.0f);
  }
}

extern "C" void kernel_launch(void* const* d_in, const int* in_sizes, int n_in,
                              void* d_out, int out_size, void* d_ws, size_t ws_size,
                              hipStream_t stream) {
  const float* eeg  = (const float*)d_in[0];
  const float* text = (const float*)d_in[1];
  float* out = (float*)d_out;
  float* ws  = (float*)d_ws;   // needs 12290 floats = 49160 B

  phaseA<<<4096, 256, 33824, stream>>>(eeg, text, ws);
  phaseB<<<1, 256, 0, stream>>>(ws);
  phaseC<<<4096, 256, 34336, stream>>>(eeg, text, ws);
  phaseD<<<1, 256, 0, stream>>>(ws, out);
}

// Round 4
// 507.891 us; speedup vs baseline: 3.8317x; 1.4443x over previous
//
#include <hip/hip_runtime.h>
#include <stdint.h>
#include <math.h>

// OptimalTransportLoss: b=64 pairs^2, n=128, d=128.
// ws floats: [0]=cost_min, [1]=cost_span, [2..8193]=per-block sq min/max pairs,
//            [8194..12289]=distances per (i,j) block.
//
// LDS (bytes): [0,16384) eL (128 rows x 32 u32 fp16-pairs, d-half)  } overlaid
//              [16384,32768) tL                                     } by Kh
//              [32768,33280) e2a | [33280,33792) t2a
//   phaseA: [33792,33824) red                       -> 33824 total
//   phaseC: [33792,34048) vh2 | [34048,34304) uh2 | [34304,34336) red -> 34336

typedef _Float16 h2 __attribute__((ext_vector_type(2)));
typedef _Float16 h8v __attribute__((ext_vector_type(8)));
typedef float f4v __attribute__((ext_vector_type(4)));

__device__ __forceinline__ h2 bch2(uint32_t u) { return __builtin_bit_cast(h2, u); }
__device__ __forceinline__ uint32_t pkh2(float x, float y) {
  h2 h = {(_Float16)x, (_Float16)y};
  return __builtin_bit_cast(uint32_t, h);
}
__device__ __forceinline__ float rnd16(float x) { return (float)(_Float16)x; }
__device__ __forceinline__ float fdot2f(h2 a, h2 b, float c) {
  return __builtin_amdgcn_fdot2(a, b, c, false);
}
// per-row LDS swizzle (u32-index XOR within a 32-u32 row): optimal b128 frag reads
__device__ __forceinline__ int swz(int r) { return ((r & 7) << 2) ^ ((r & 8) << 1); }

// Stage d-half p (cols 64p..64p+63) of eeg[i], text[j] into LDS as fp16 pairs.
__device__ __forceinline__ void stageHalf(const float* __restrict__ ep,
                                          const float* __restrict__ tp,
                                          uint32_t* eL, uint32_t* tL, int t, int p) {
  const float4* e4 = (const float4*)ep;
  const float4* t4 = (const float4*)tp;
#pragma unroll
  for (int k = 0; k < 8; ++k) {
    int F = k * 256 + t;          // 0..2047
    int m = F >> 4, g = F & 15;   // row, float4-group within half
    int src = m * 32 + 16 * p + g;
    int idx = m * 32 + ((2 * g) ^ swz(m));   // even; +1 adjacent (swz has no bit0)
    float4 x = e4[src];
    *(uint2*)(eL + idx) = make_uint2(pkh2(x.x, x.y), pkh2(x.z, x.w));
    float4 y = t4[src];
    *(uint2*)(tL + idx) = make_uint2(pkh2(y.x, y.y), pkh2(y.z, y.w));
  }
}

// fp16 squared-norm partial for this thread's row over one half (order-stable).
__device__ __forceinline__ void normPartial(const uint32_t* eL, const uint32_t* tL,
                                            int t, float& a0, float& a1) {
  int r = t & 127;
  const uint32_t* base = ((t < 128) ? eL : tL) + r * 32;
  int sw = swz(r);
#pragma unroll
  for (int kl = 0; kl < 16; ++kl) {
    uint2 u = *(const uint2*)(base + ((2 * kl) ^ sw));
    h2 x = bch2(u.x), y = bch2(u.y);
    a0 = fdot2f(x, x, a0);
    a1 = fdot2f(y, y, a1);
  }
}

// MFMA build over one d-half (2 k-steps of 32). Wave w owns C rows 32w..32w+31.
// acc[i][tc] tile: rows 16*(2w+i)+0..15, cols 16*tc+0..15.
// Lane l (lr=l&15, lg=l>>4): A/B frag = 8 halves at row(+lr), u32 off (ks*16+lg*4)^swz.
// C/D map (m89-verified): value j of acc -> row 16*(2w+i)+4*lg+j, col 16*tc+lr.
__device__ __forceinline__ void buildMfma(const uint32_t* eL, const uint32_t* tL,
                                          int w, int lr, int lg, f4v (&acc)[2][8]) {
#pragma unroll
  for (int ks = 0; ks < 2; ++ks) {
    int off = ks * 16 + lg * 4;
    int r0 = 32 * w + lr, r1 = r0 + 16;
    h8v A0 = *(const h8v*)(eL + r0 * 32 + (off ^ swz(r0)));
    h8v A1 = *(const h8v*)(eL + r1 * 32 + (off ^ swz(r1)));
#pragma unroll
    for (int tg = 0; tg < 2; ++tg) {
      h8v B[4];
#pragma unroll
      for (int q = 0; q < 4; ++q) {
        int rt = (4 * tg + q) * 16 + lr;
        B[q] = *(const h8v*)(tL + rt * 32 + (off ^ swz(rt)));
      }
#pragma unroll
      for (int q = 0; q < 4; ++q) {
        acc[0][4 * tg + q] = __builtin_amdgcn_mfma_f32_16x16x32_f16(A0, B[q], acc[0][4 * tg + q], 0, 0, 0);
        acc[1][4 * tg + q] = __builtin_amdgcn_mfma_f32_16x16x32_f16(A1, B[q], acc[1][4 * tg + q], 0, 0, 0);
      }
    }
  }
}

// ---------------- Phase A: per-block min/max of sq (pre-sqrt, monotone) -------------
__attribute__((amdgpu_waves_per_eu(4, 4)))
__global__ __launch_bounds__(256) void phaseA(const float* __restrict__ eeg,
                                              const float* __restrict__ text,
                                              float* __restrict__ ws) {
  extern __shared__ char smem[];
  uint32_t* eL = (uint32_t*)smem;
  uint32_t* tL = (uint32_t*)(smem + 16384);
  float* e2a   = (float*)(smem + 32768);
  float* t2a   = (float*)(smem + 33280);
  float* red   = (float*)(smem + 33792);
  int t = threadIdx.x, b = blockIdx.x;
  const float* ep = eeg + (size_t)(b >> 6) * 16384;
  const float* tp = text + (size_t)(b & 63) * 16384;

  int w = t >> 6, lr = t & 15, lg = (t >> 4) & 3;
  f4v acc[2][8];
#pragma unroll
  for (int i = 0; i < 2; ++i)
#pragma unroll
    for (int tc = 0; tc < 8; ++tc) acc[i][tc] = (f4v){0.f, 0.f, 0.f, 0.f};
  float na0 = 0.f, na1 = 0.f;

  stageHalf(ep, tp, eL, tL, t, 0);
  __syncthreads();
  normPartial(eL, tL, t, na0, na1);
  buildMfma(eL, tL, w, lr, lg, acc);
  __syncthreads();
  stageHalf(ep, tp, eL, tL, t, 1);
  __syncthreads();
  normPartial(eL, tL, t, na0, na1);
  {
    int r = t & 127;
    float nn = rnd16(na0 + na1);
    if (t < 128) e2a[r] = nn; else t2a[r] = nn;
  }
  buildMfma(eL, tL, w, lr, lg, acc);
  __syncthreads();

  float e2x[2][4], t2x[8];
#pragma unroll
  for (int i = 0; i < 2; ++i)
#pragma unroll
    for (int j = 0; j < 4; ++j) e2x[i][j] = e2a[32 * w + 16 * i + 4 * lg + j];
#pragma unroll
  for (int tc = 0; tc < 8; ++tc) t2x[tc] = t2a[16 * tc + lr];

  float smn = 1e30f, smx = -1e30f;
#pragma unroll
  for (int i = 0; i < 2; ++i)
#pragma unroll
    for (int tc = 0; tc < 8; ++tc)
#pragma unroll
      for (int j = 0; j < 4; ++j) {
        float ip = rnd16(acc[i][tc][j]);
        float sq = fmaxf(fmaf(-2.0f, ip, e2x[i][j] + t2x[tc]), 0.0f);
        smn = fminf(smn, sq);
        smx = fmaxf(smx, sq);
      }
#pragma unroll
  for (int msk = 1; msk < 64; msk <<= 1) {
    smn = fminf(smn, __shfl_xor(smn, msk));
    smx = fmaxf(smx, __shfl_xor(smx, msk));
  }
  if ((t & 63) == 0) { red[t >> 6] = smn; red[4 + (t >> 6)] = smx; }
  __syncthreads();
  if (t == 0) {
    float mn = fminf(fminf(red[0], red[1]), fminf(red[2], red[3]));
    float mx = fmaxf(fmaxf(red[4], red[5]), fmaxf(red[6], red[7]));
    ws[2 + 2 * b] = mn;
    ws[3 + 2 * b] = mx;
  }
}

// ---------------- Phase B: reduce 4096 block min/max -> cost_min, cost_span ---------
__global__ void phaseB(float* __restrict__ ws) {
  __shared__ float red[16];
  int t = threadIdx.x;
  float mn = 1e30f, mx = -1e30f;
#pragma unroll
  for (int k = 0; k < 16; ++k) {
    int idx = k * 256 + t;
    mn = fminf(mn, ws[2 + 2 * idx]);
    mx = fmaxf(mx, ws[3 + 2 * idx]);
  }
#pragma unroll
  for (int msk = 1; msk < 64; msk <<= 1) {
    mn = fminf(mn, __shfl_xor(mn, msk));
    mx = fmaxf(mx, __shfl_xor(mx, msk));
  }
  if ((t & 63) == 0) { red[t >> 6] = mn; red[8 + (t >> 6)] = mx; }
  __syncthreads();
  if (t == 0) {
    mn = fminf(fminf(red[0], red[1]), fminf(red[2], red[3]));
    mx = fmaxf(fmaxf(red[8], red[9]), fmaxf(red[10], red[11]));
    float cmn = rnd16(sqrtf(rnd16(mn)));
    float cmx = rnd16(sqrtf(rnd16(mx)));
    ws[0] = cmn;
    ws[1] = cmx - cmn;
  }
}

// ---------------- Phase C: MFMA cost build + register-resident Sinkhorn -------------
// K' = 2^8 * exp(-(c-cmn)/(0.1*span)) stored fp16 (all normal: [0.0116,256]).
__attribute__((amdgpu_waves_per_eu(4, 4)))
__global__ __launch_bounds__(256) void phaseC(const float* __restrict__ eeg,
                                              const float* __restrict__ text,
                                              float* __restrict__ ws) {
  extern __shared__ char smem[];
  uint32_t* eL  = (uint32_t*)smem;
  uint32_t* tL  = (uint32_t*)(smem + 16384);
  uint32_t* Kh  = (uint32_t*)smem;              // 8192 u32 overlay
  float* e2a    = (float*)(smem + 32768);
  float* t2a    = (float*)(smem + 33280);
  uint32_t* vh2 = (uint32_t*)(smem + 33792);
  uint32_t* uh2 = (uint32_t*)(smem + 34048);
  float* red    = (float*)(smem + 34304);
  int t = threadIdx.x, b = blockIdx.x;
  const float* ep = eeg + (size_t)(b >> 6) * 16384;
  const float* tp = text + (size_t)(b & 63) * 16384;

  int w = t >> 6, lr = t & 15, lg = (t >> 4) & 3;
  f4v acc[2][8];
#pragma unroll
  for (int i = 0; i < 2; ++i)
#pragma unroll
    for (int tc = 0; tc < 8; ++tc) acc[i][tc] = (f4v){0.f, 0.f, 0.f, 0.f};
  float na0 = 0.f, na1 = 0.f;

  stageHalf(ep, tp, eL, tL, t, 0);
  __syncthreads();
  normPartial(eL, tL, t, na0, na1);
  buildMfma(eL, tL, w, lr, lg, acc);
  __syncthreads();
  stageHalf(ep, tp, eL, tL, t, 1);
  __syncthreads();
  normPartial(eL, tL, t, na0, na1);
  {
    int r = t & 127;
    float nn = rnd16(na0 + na1);
    if (t < 128) e2a[r] = nn; else t2a[r] = nn;
  }
  buildMfma(eL, tL, w, lr, lg, acc);
  __syncthreads();   // eL/tL reads done; e2a/t2a visible; Kh overlay now safe

  float cmn = ws[0];
  float kexp2 = 1.4426950408889634f / (0.1f * ws[1]);  // log2e/(reg*span)

  float e2x[2][4], t2x[8];
#pragma unroll
  for (int i = 0; i < 2; ++i)
#pragma unroll
    for (int j = 0; j < 4; ++j) e2x[i][j] = e2a[32 * w + 16 * i + 4 * lg + j];
#pragma unroll
  for (int tc = 0; tc < 8; ++tc) t2x[tc] = t2a[16 * tc + lr];

  // K-build: per element -> fp16 bits into Kh with rotation swizzle
  //   pos(hc,row) = (((hc>>2)+(row>>1))&15)*4 + (hc&3), hc = col>>1
  uint16_t* Kh16 = (uint16_t*)Kh;
  float ks = 0.f;
#pragma unroll
  for (int i = 0; i < 2; ++i)
#pragma unroll
    for (int tc = 0; tc < 8; ++tc)
#pragma unroll
      for (int j = 0; j < 4; ++j) {
        int row = 32 * w + 16 * i + 4 * lg + j;
        int col = 16 * tc + lr;
        float ip = rnd16(acc[i][tc][j]);
        float sq = fmaxf(fmaf(-2.0f, ip, e2x[i][j] + t2x[tc]), 0.0f);
        float c  = rnd16(sqrtf(rnd16(sq)));
        float kf = exp2f(fmaf(cmn - c, kexp2, 8.0f));   // 2^8-scaled kernel
        ks += kf;
        int hc = col >> 1;
        int pos = (((hc >> 2) + (row >> 1)) & 15) * 4 + (hc & 3);
        Kh16[(row * 64 + pos) * 2 + (col & 1)] = __builtin_bit_cast(uint16_t, (_Float16)kf);
      }
#pragma unroll
  for (int msk = 1; msk < 64; msk <<= 1) ks += __shfl_xor(ks, msk);
  if ((t & 63) == 0) red[t >> 6] = ks;
  __syncthreads();
  float Sp = (red[0] + red[1]) + (red[2] + red[3]);   // = 256 * sum(K)
  float u0 = 256.0f / Sp;                              // = 1/sum(K)
  if (t < 64) { vh2[t] = 0x3C003C00u; uh2[t] = pkh2(u0, u0); }

  // Register tiles: lane (w,a,bq): rows n0,n0+1 (kk0/kk1), cols 2nh,2nh+1 (kt0/kt1).
  int l = t & 63, a = l >> 2, bq = l & 3;
  int n0 = 32 * w + 2 * a;
  int nh = 16 * w + a;
  uint32_t kk0[16], kk1[16], kt0[16], kt1[16];
#pragma unroll
  for (int q = 0; q < 4; ++q) {
    int grp = (4 * bq + q + nh) & 15;
    uint4 x0 = *(const uint4*)(Kh + n0 * 64 + grp * 4);
    uint4 x1 = *(const uint4*)(Kh + (n0 + 1) * 64 + grp * 4);
    kk0[4 * q] = x0.x; kk0[4 * q + 1] = x0.y; kk0[4 * q + 2] = x0.z; kk0[4 * q + 3] = x0.w;
    kk1[4 * q] = x1.x; kk1[4 * q + 1] = x1.y; kk1[4 * q + 2] = x1.z; kk1[4 * q + 3] = x1.w;
  }
  int cgk = nh >> 2, pos4 = a & 3;
#pragma unroll
  for (int k = 0; k < 16; ++k) {
    int r0 = 32 * bq + 2 * k;
    int rh = 16 * bq + k;
    uint32_t v0 = Kh[r0 * 64 + (((cgk + rh) & 15) * 4 + pos4)];
    uint32_t v1 = Kh[(r0 + 1) * 64 + (((cgk + rh) & 15) * 4 + pos4)];
    kt0[k] = __builtin_amdgcn_perm(v1, v0, 0x05040100u);  // (lo,lo): col 2nh
    kt1[k] = __builtin_amdgcn_perm(v1, v0, 0x07060302u);  // (hi,hi): col 2nh+1
  }
  __syncthreads();   // uh2/vh2 init visible

  float uf0 = u0, uf1 = u0, vf0 = 1.0f, vf1 = 1.0f;

  for (int it = 0; it < 100; ++it) {
    // row sweep: w = K v ; u <- u / (u*w + 1e-8)
    uint32_t vh[16];
#pragma unroll
    for (int q = 0; q < 4; ++q) {
      uint4 x = *(const uint4*)(vh2 + 16 * bq + 4 * q);
      vh[4 * q] = x.x; vh[4 * q + 1] = x.y; vh[4 * q + 2] = x.z; vh[4 * q + 3] = x.w;
    }
    float w0a = 0.f, w0b = 0.f, w1a = 0.f, w1b = 0.f;
#pragma unroll
    for (int k = 0; k < 8; ++k) {
      w0a = fdot2f(bch2(kk0[k]),     bch2(vh[k]),     w0a);
      w0b = fdot2f(bch2(kk0[k + 8]), bch2(vh[k + 8]), w0b);
      w1a = fdot2f(bch2(kk1[k]),     bch2(vh[k]),     w1a);
      w1b = fdot2f(bch2(kk1[k + 8]), bch2(vh[k + 8]), w1b);
    }
    float w0 = w0a + w0b, w1 = w1a + w1b;
    w0 += __shfl_xor(w0, 1); w0 += __shfl_xor(w0, 2);
    w1 += __shfl_xor(w1, 1); w1 += __shfl_xor(w1, 2);
    float d0 = fmaf(uf0, w0 * 0x1p-8f, 1e-8f);
    float d1 = fmaf(uf1, w1 * 0x1p-8f, 1e-8f);
    uf0 = uf0 * __builtin_amdgcn_rcpf(d0);
    uf1 = uf1 * __builtin_amdgcn_rcpf(d1);
    if (bq == 0) uh2[nh] = pkh2(uf0, uf1);
    __syncthreads();

    // col sweep: z = K^T u ; v <- v / (v*z + 1e-8)
    uint32_t uh[16];
#pragma unroll
    for (int q = 0; q < 4; ++q) {
      uint4 x = *(const uint4*)(uh2 + 16 * bq + 4 * q);
      uh[4 * q] = x.x; uh[4 * q + 1] = x.y; uh[4 * q + 2] = x.z; uh[4 * q + 3] = x.w;
    }
    float z0a = 0.f, z0b = 0.f, z1a = 0.f, z1b = 0.f;
#pragma unroll
    for (int k = 0; k < 8; ++k) {
      z0a = fdot2f(bch2(kt0[k]),     bch2(uh[k]),     z0a);
      z0b = fdot2f(bch2(kt0[k + 8]), bch2(uh[k + 8]), z0b);
      z1a = fdot2f(bch2(kt1[k]),     bch2(uh[k]),     z1a);
      z1b = fdot2f(bch2(kt1[k + 8]), bch2(uh[k + 8]), z1b);
    }
    float z0 = z0a + z0b, z1 = z1a + z1b;
    z0 += __shfl_xor(z0, 1); z0 += __shfl_xor(z0, 2);
    z1 += __shfl_xor(z1, 1); z1 += __shfl_xor(z1, 2);
    float e0 = fmaf(vf0, z0 * 0x1p-8f, 1e-8f);
    float e1 = fmaf(vf1, z1 * 0x1p-8f, 1e-8f);
    vf0 = vf0 * __builtin_amdgcn_rcpf(e0);
    vf1 = vf1 * __builtin_amdgcn_rcpf(e1);
    if (bq == 0) vh2[nh] = pkh2(vf0, vf1);
    __syncthreads();
  }

  // distance = sum u K v * cost_n ; cost_n = 0.1*ln2*(8 - log2(K'))
  {
    uint32_t vh[16];
#pragma unroll
    for (int q = 0; q < 4; ++q) {
      uint4 x = *(const uint4*)(vh2 + 16 * bq + 4 * q);
      vh[4 * q] = x.x; vh[4 * q + 1] = x.y; vh[4 * q + 2] = x.z; vh[4 * q + 3] = x.w;
    }
    float acc0 = 0.f, acc1 = 0.f;
#pragma unroll
    for (int k = 0; k < 16; ++k) {
      h2 vp = bch2(vh[k]);
      h2 k0 = bch2(kk0[k]);
      h2 k1 = bch2(kk1[k]);
      float kf, vf;
      kf = (float)k0[0]; vf = (float)vp[0]; acc0 += kf * vf * (8.0f - __log2f(kf));
      kf = (float)k0[1]; vf = (float)vp[1]; acc0 += kf * vf * (8.0f - __log2f(kf));
      kf = (float)k1[0]; vf = (float)vp[0]; acc1 += kf * vf * (8.0f - __log2f(kf));
      kf = (float)k1[1]; vf = (float)vp[1]; acc1 += kf * vf * (8.0f - __log2f(kf));
    }
    float tot = (uf0 * acc0 + uf1 * acc1) * (0.069314718055994531f * 0x1p-8f);
#pragma unroll
    for (int msk = 1; msk < 64; msk <<= 1) tot += __shfl_xor(tot, msk);
    if (l == 0) red[w] = tot;
    __syncthreads();
    if (t == 0) ws[8194 + b] = (red[0] + red[1]) + (red[2] + red[3]);
  }
}

// ---------------- Phase D: minmax(d) -> similarity -> CE loss ------------------------
__global__ void phaseD(const float* __restrict__ ws, float* __restrict__ out) {
  __shared__ float sim[4096];
  __shared__ float red[16];
  int t = threadIdx.x;
  const float* d = ws + 8194;
  float dv[16];
  float mn = 1e30f, mx = -1e30f;
#pragma unroll
  for (int k = 0; k < 16; ++k) {
    dv[k] = d[k * 256 + t];
    mn = fminf(mn, dv[k]);
    mx = fmaxf(mx, dv[k]);
  }
#pragma unroll
  for (int msk = 1; msk < 64; msk <<= 1) {
    mn = fminf(mn, __shfl_xor(mn, msk));
    mx = fmaxf(mx, __shfl_xor(mx, msk));
  }
  if ((t & 63) == 0) { red[t >> 6] = mn; red[8 + (t >> 6)] = mx; }
  __syncthreads();
  mn = fminf(fminf(red[0], red[1]), fminf(red[2], red[3]));
  mx = fmaxf(fmaxf(red[8], red[9]), fmaxf(red[10], red[11]));
  float inv = 1.0f / (mx - mn);
#pragma unroll
  for (int k = 0; k < 16; ++k) {
    int idx = k * 256 + t;
    float s = expf(-(dv[k] - mn) * inv);
    sim[idx] = s;
    out[1 + idx] = s;
  }
  __syncthreads();
  if (t < 64) {
    float a = 0.f;
    for (int j = 0; j < 64; ++j) a += expf(sim[t * 64 + j]);
    float val = logf(a) - sim[t * 64 + t];
#pragma unroll
    for (int msk = 1; msk < 64; msk <<= 1) val += __shfl_xor(val, msk);
    if (t == 0) out[0] = val * (1.0f / 64.0f);
  }
}

extern "C" void kernel_launch(void* const* d_in, const int* in_sizes, int n_in,
                              void* d_out, int out_size, void* d_ws, size_t ws_size,
                              hipStream_t stream) {
  const float* eeg  = (const float*)d_in[0];
  const float* text = (const float*)d_in[1];
  float* out = (float*)d_out;
  float* ws  = (float*)d_ws;   // needs 12290 floats = 49160 B

  phaseA<<<4096, 256, 33824, stream>>>(eeg, text, ws);
  phaseB<<<1, 256, 0, stream>>>(ws);
  phaseC<<<4096, 256, 34336, stream>>>(eeg, text, ws);
  phaseD<<<1, 256, 0, stream>>>(ws, out);
}